// Round 1
// baseline (2789.443 us; speedup 1.0000x reference)
//
#include <hip/hip_runtime.h>
#include <hip/hip_bf16.h>
#include <math.h>

#define S    2048
#define HQ   16
#define D    128
#define HI   16
#define DI   128
#define KSEL 512

// ---------------- reductions (wave = 64) ----------------
__device__ __forceinline__ float waveReduceSum(float v) {
#pragma unroll
    for (int o = 32; o > 0; o >>= 1) v += __shfl_down(v, o);
    return v;
}
__device__ __forceinline__ float waveReduceMax(float v) {
#pragma unroll
    for (int o = 32; o > 0; o >>= 1) v = fmaxf(v, __shfl_down(v, o));
    return v;
}
// safe to call repeatedly: leading barrier protects tmp from previous read
__device__ __forceinline__ float blockReduceSum(float v, float* tmp) {
    int wid = threadIdx.x >> 6, lane = threadIdx.x & 63;
    v = waveReduceSum(v);
    __syncthreads();
    if (lane == 0) tmp[wid] = v;
    __syncthreads();
    return tmp[0] + tmp[1] + tmp[2] + tmp[3];
}
__device__ __forceinline__ float blockReduceMax(float v, float* tmp) {
    int wid = threadIdx.x >> 6, lane = threadIdx.x & 63;
    v = waveReduceMax(v);
    __syncthreads();
    if (lane == 0) tmp[wid] = v;
    __syncthreads();
    return fmaxf(fmaxf(tmp[0], tmp[1]), fmaxf(tmp[2], tmp[3]));
}

// ---------------- Kernel A: indexer row + radix top-k ----------------
// block = 256 threads, grid = S (one block per query row q)
__global__ __launch_bounds__(256) void indexer_topk(
    const float* __restrict__ qi,   // [S, HI, DI]
    const float* __restrict__ ki,   // [S, DI]
    const float* __restrict__ w,    // [S, HI]
    const int* __restrict__ topk_p, const int* __restrict__ endpos_p,
    int* __restrict__ topk_idx,     // [S, KSEL]
    float* __restrict__ topk_score) // [S, KSEL]
{
    const int q   = blockIdx.x;
    const int tid = threadIdx.x;
    int K = min(topk_p[0], endpos_p[0]);
    K = min(K, KSEL);

    __shared__ float qis[HI * DI];     // 8 KB
    __shared__ float wsh[HI];
    __shared__ float scores[S];        // 8 KB
    __shared__ unsigned int bins[256]; // 1 KB
    __shared__ unsigned int sh_u[3];
    __shared__ unsigned int cnt;

    for (int i = tid; i < HI * DI; i += 256) qis[i] = qi[(size_t)q * HI * DI + i];
    if (tid < HI) wsh[tid] = w[q * HI + tid];
    __syncthreads();

    const int ncand = q + 1;

    // ---- scores[k] for k in [0, q]: 4-k register blocking, h x 4d inner ----
    for (int kbase = 0; kbase < ncand; kbase += 1024) {
        const int k0 = kbase + tid * 4;
        if (k0 < ncand) {   // whole 4-group past q -> skip entirely
            float acc[4][HI];
#pragma unroll
            for (int a = 0; a < 4; a++)
#pragma unroll
                for (int h = 0; h < HI; h++) acc[a][h] = 0.f;
            for (int d0 = 0; d0 < DI; d0 += 4) {
                float4 kv[4];
#pragma unroll
                for (int a = 0; a < 4; a++)
                    kv[a] = *(const float4*)&ki[(size_t)(k0 + a) * DI + d0];
#pragma unroll
                for (int h = 0; h < HI; h++) {
                    float4 qv = *(const float4*)&qis[h * DI + d0];
#pragma unroll
                    for (int a = 0; a < 4; a++) {
                        acc[a][h] += qv.x * kv[a].x + qv.y * kv[a].y +
                                     qv.z * kv[a].z + qv.w * kv[a].w;
                    }
                }
            }
#pragma unroll
            for (int a = 0; a < 4; a++) {
                int k = k0 + a;
                if (k < ncand) {
                    float s = 0.f;
#pragma unroll
                    for (int h = 0; h < HI; h++) s += wsh[h] * fmaxf(acc[a][h], 0.f);
                    scores[k] = s;
                }
            }
        }
    }
    __syncthreads();

    // ---- trivial case: all candidates selected ----
    if (ncand <= K) {
        for (int j = tid; j < KSEL; j += 256) {
            if (j < ncand) {
                topk_idx[q * KSEL + j]   = j;
                topk_score[q * KSEL + j] = scores[j];
            } else {
                topk_idx[q * KSEL + j]   = -1;
                topk_score[q * KSEL + j] = -INFINITY;
            }
        }
        return;
    }

    // ---- radix select: scores >= 0 so float bits are order-isomorphic ----
    unsigned int prefix = 0;
    int need = K;   // how many still to pick among values == eventual threshold
    int cgt  = 0;   // count strictly greater than threshold
    for (int pass = 0; pass < 4; ++pass) {
        const int shift = 24 - pass * 8;
        for (int b = tid; b < 256; b += 256) bins[b] = 0;
        __syncthreads();
        const unsigned int himask = (pass == 0) ? 0u : (0xFFFFFFFFu << (shift + 8));
        for (int k = tid; k < ncand; k += 256) {
            unsigned int u = __float_as_uint(scores[k]);
            if ((u & himask) == prefix) atomicAdd(&bins[(u >> shift) & 0xFF], 1u);
        }
        __syncthreads();
        if (tid == 0) {
            int nd = need, acc_gt = 0, b;
            for (b = 255; b >= 1; --b) {
                int c = (int)bins[b];
                if (c >= nd) break;
                nd -= c; acc_gt += c;
            }
            sh_u[0] = prefix | ((unsigned int)b << shift);
            sh_u[1] = (unsigned int)nd;
            sh_u[2] = (unsigned int)acc_gt;
        }
        __syncthreads();
        prefix = sh_u[0];
        need   = (int)sh_u[1];
        cgt   += (int)sh_u[2];
        __syncthreads();
    }
    const unsigned int ueqT = prefix;       // exact bits of K-th largest value
    const int count_eq = (int)bins[ueqT & 0xFF];
    __syncthreads();
    if (tid == 0) cnt = 0;
    __syncthreads();

    // emit strictly-greater (order within slots is irrelevant: downstream is
    // permutation-invariant over (idx,score) pairs)
    for (int k = tid; k < ncand; k += 256) {
        unsigned int u = __float_as_uint(scores[k]);
        if (u > ueqT) {
            unsigned int slot = atomicAdd(&cnt, 1u);
            topk_idx[q * KSEL + slot]   = k;
            topk_score[q * KSEL + slot] = scores[k];
        }
    }
    __syncthreads();
    // emit equals (ties: jax.lax.top_k keeps lowest index first)
    if (count_eq == need) {
        for (int k = tid; k < ncand; k += 256) {
            if (__float_as_uint(scores[k]) == ueqT) {
                unsigned int slot = atomicAdd(&cnt, 1u);
                topk_idx[q * KSEL + slot]   = k;
                topk_score[q * KSEL + slot] = __uint_as_float(ueqT);
            }
        }
    } else if (tid == 0) {  // rare tie path: ordered serial scan
        int emitted = 0;
        for (int k = 0; k < ncand && emitted < need; ++k) {
            if (__float_as_uint(scores[k]) == ueqT) {
                unsigned int slot = atomicAdd(&cnt, 1u);
                topk_idx[q * KSEL + slot]   = k;
                topk_score[q * KSEL + slot] = __uint_as_float(ueqT);
                emitted++;
            }
        }
    }
}

// ---------------- Kernel B: gather SDPA over selected keys + row KL ----------------
// block = 256 threads, grid = S (one block per query row q), heads looped inside
__global__ __launch_bounds__(256) void sparse_attn(
    const float* __restrict__ Q,    // [HQ, S, D]
    const float* __restrict__ Km,   // [HQ, S, D]
    const float* __restrict__ V,    // [HQ, S, D]
    const int* __restrict__ topk_idx,
    const float* __restrict__ topk_score,
    const int* __restrict__ topk_p, const int* __restrict__ endpos_p,
    float* __restrict__ out,        // [HQ, S, D]
    float* __restrict__ rowloss)    // [S]
{
    const int q   = blockIdx.x;
    const int tid = threadIdx.x;
    int K = min(topk_p[0], endpos_p[0]);
    K = min(K, KSEL);
    const int n = min(q + 1, K);
    const float scale = 0.08838834764831845f; // 1/sqrt(128)

    __shared__ int   idxs[KSEL];      // 2 KB
    __shared__ float sc[KSEL];        // 2 KB  (scores -> probs)
    __shared__ float aacc[KSEL];      // 2 KB  (sum over heads of attn)
    __shared__ float qvec[D];
    __shared__ float opart[8][D];     // 4 KB
    __shared__ float tmp[4];

    for (int j = tid; j < KSEL; j += 256) {
        idxs[j] = (j < n) ? topk_idx[q * KSEL + j] : 0;
        aacc[j] = 0.f;
    }
    __syncthreads();

    for (int h = 0; h < HQ; ++h) {
        for (int d = tid; d < D; d += 256) qvec[d] = Q[((size_t)h * S + q) * D + d];
        __syncthreads();

        // gather-QK: per selected slot j, dot(qvec, K[h, idxs[j]])
        float lmax = -INFINITY;
        for (int j = tid; j < n; j += 256) {
            const float* kr = &Km[((size_t)h * S + idxs[j]) * D];
            float acc = 0.f;
            for (int d0 = 0; d0 < D; d0 += 4) {
                float4 kv = *(const float4*)&kr[d0];
                float4 qv = *(const float4*)&qvec[d0];
                acc += qv.x * kv.x + qv.y * kv.y + qv.z * kv.z + qv.w * kv.w;
            }
            float s = acc * scale;
            sc[j] = s;
            lmax = fmaxf(lmax, s);
        }
        const float m = blockReduceMax(lmax, tmp);

        float lsum = 0.f;
        for (int j = tid; j < n; j += 256) {
            float p = expf(sc[j] - m);
            sc[j] = p;
            lsum += p;
        }
        lsum = blockReduceSum(lsum, tmp);
        const float inv = 1.f / lsum;
        for (int j = tid; j < n; j += 256) {
            float p = sc[j] * inv;
            sc[j] = p;          // normalized attn prob
            aacc[j] += p;       // head-summed attn at this slot
        }
        __syncthreads();

        // gather-PV: 8-way split over j, float4 over d (coalesced per row)
        const int part = tid >> 5;          // 0..7
        const int dd   = (tid & 31) * 4;    // 0..124
        const int per  = (n + 7) >> 3;
        const int j0 = part * per, j1 = min(n, j0 + per);
        float4 o4 = make_float4(0.f, 0.f, 0.f, 0.f);
        for (int j = j0; j < j1; ++j) {
            const float p = sc[j];
            float4 vv = *(const float4*)&V[((size_t)h * S + idxs[j]) * D + dd];
            o4.x += p * vv.x; o4.y += p * vv.y; o4.z += p * vv.z; o4.w += p * vv.w;
        }
        *(float4*)&opart[part][dd] = o4;
        __syncthreads();
        if (tid < D) {
            float o = 0.f;
#pragma unroll
            for (int p8 = 0; p8 < 8; ++p8) o += opart[p8][tid];
            out[((size_t)h * S + q) * D + tid] = o;
        }
        __syncthreads();
    }

    // ---- row KL loss: pdist = softmax(topk_score), tgt = aacc / sum ----
    float tmaxl = -INFINITY;
    for (int j = tid; j < n; j += 256) {
        float t = topk_score[q * KSEL + j];
        sc[j] = t;
        tmaxl = fmaxf(tmaxl, t);
    }
    const float tm = blockReduceMax(tmaxl, tmp);
    float tsum = 0.f;
    for (int j = tid; j < n; j += 256) {
        float e = expf(sc[j] - tm);
        sc[j] = e;
        tsum += e;
    }
    tsum = blockReduceSum(tsum, tmp);
    const float tinv = 1.f / tsum;

    float sa = 0.f;
    for (int j = tid; j < n; j += 256) sa += fabsf(aacc[j]);
    sa = blockReduceSum(sa, tmp);
    const float denom = fmaxf(sa, 1e-12f);

    float kl = 0.f;
    for (int j = tid; j < n; j += 256) {
        float tgt = aacc[j] / denom + 1e-8f;
        float pd  = sc[j] * tinv + 1e-8f;
        kl += tgt * (logf(tgt) - logf(pd));
    }
    kl = blockReduceSum(kl, tmp);
    if (tid == 0) rowloss[q] = kl;
}

// ---------------- Kernel C: loss = mean over rows ----------------
__global__ __launch_bounds__(256) void reduce_loss(const float* __restrict__ rowloss,
                                                   float* __restrict__ out) {
    __shared__ float tmp[4];
    float v = 0.f;
    for (int i = threadIdx.x; i < S; i += 256) v += rowloss[i];
    v = blockReduceSum(v, tmp);
    if (threadIdx.x == 0) out[0] = v / (float)S;
}

extern "C" void kernel_launch(void* const* d_in, const int* in_sizes, int n_in,
                              void* d_out, int out_size, void* d_ws, size_t ws_size,
                              hipStream_t stream) {
    const float* q   = (const float*)d_in[0];
    const float* k   = (const float*)d_in[1];
    const float* v   = (const float*)d_in[2];
    const float* qi  = (const float*)d_in[3];
    const float* ki  = (const float*)d_in[4];
    const float* w   = (const float*)d_in[5];
    const int* topk  = (const int*)d_in[6];
    const int* endp  = (const int*)d_in[7];
    float* out = (float*)d_out;

    char* ws = (char*)d_ws;
    int*   topk_idx   = (int*)ws;                                  // 4 MB
    float* topk_score = (float*)(ws + (size_t)S * KSEL * 4);       // 4 MB
    float* rowloss    = (float*)(ws + (size_t)S * KSEL * 8);       // 8 KB

    hipLaunchKernelGGL(indexer_topk, dim3(S), dim3(256), 0, stream,
                       qi, ki, w, topk, endp, topk_idx, topk_score);
    hipLaunchKernelGGL(sparse_attn, dim3(S), dim3(256), 0, stream,
                       q, k, v, topk_idx, topk_score, topk, endp,
                       out + 1, rowloss);
    hipLaunchKernelGGL(reduce_loss, dim3(1), dim3(256), 0, stream,
                       rowloss, out);
}

// Round 2
// 867.887 us; speedup vs baseline: 3.2141x; 3.2141x over previous
//
#include <hip/hip_runtime.h>
#include <hip/hip_bf16.h>
#include <math.h>

#define S    2048
#define HQ   16
#define D    128
#define HI   16
#define DI   128
#define KSEL 512

// ---------------- reductions (wave = 64) ----------------
__device__ __forceinline__ float waveReduceSum(float v) {
#pragma unroll
    for (int o = 32; o > 0; o >>= 1) v += __shfl_down(v, o);
    return v;
}
__device__ __forceinline__ float waveReduceMax(float v) {
#pragma unroll
    for (int o = 32; o > 0; o >>= 1) v = fmaxf(v, __shfl_down(v, o));
    return v;
}
// safe to call repeatedly: leading barrier protects tmp from previous read
__device__ __forceinline__ float blockReduceSum(float v, float* tmp) {
    int wid = threadIdx.x >> 6, lane = threadIdx.x & 63;
    v = waveReduceSum(v);
    __syncthreads();
    if (lane == 0) tmp[wid] = v;
    __syncthreads();
    return tmp[0] + tmp[1] + tmp[2] + tmp[3];
}
__device__ __forceinline__ float blockReduceMax(float v, float* tmp) {
    int wid = threadIdx.x >> 6, lane = threadIdx.x & 63;
    v = waveReduceMax(v);
    __syncthreads();
    if (lane == 0) tmp[wid] = v;
    __syncthreads();
    return fmaxf(fmaxf(tmp[0], tmp[1]), fmaxf(tmp[2], tmp[3]));
}

// ---------------- Kernel A: indexer row + radix top-k (unchanged) ----------------
__global__ __launch_bounds__(256) void indexer_topk(
    const float* __restrict__ qi,   // [S, HI, DI]
    const float* __restrict__ ki,   // [S, DI]
    const float* __restrict__ w,    // [S, HI]
    const int* __restrict__ topk_p, const int* __restrict__ endpos_p,
    int* __restrict__ topk_idx,     // [S, KSEL]
    float* __restrict__ topk_score) // [S, KSEL]
{
    const int q   = blockIdx.x;
    const int tid = threadIdx.x;
    int K = min(topk_p[0], endpos_p[0]);
    K = min(K, KSEL);

    __shared__ float qis[HI * DI];     // 8 KB
    __shared__ float wsh[HI];
    __shared__ float scores[S];        // 8 KB
    __shared__ unsigned int bins[256]; // 1 KB
    __shared__ unsigned int sh_u[3];
    __shared__ unsigned int cnt;

    for (int i = tid; i < HI * DI; i += 256) qis[i] = qi[(size_t)q * HI * DI + i];
    if (tid < HI) wsh[tid] = w[q * HI + tid];
    __syncthreads();

    const int ncand = q + 1;

    for (int kbase = 0; kbase < ncand; kbase += 1024) {
        const int k0 = kbase + tid * 4;
        if (k0 < ncand) {
            float acc[4][HI];
#pragma unroll
            for (int a = 0; a < 4; a++)
#pragma unroll
                for (int h = 0; h < HI; h++) acc[a][h] = 0.f;
            for (int d0 = 0; d0 < DI; d0 += 4) {
                float4 kv[4];
#pragma unroll
                for (int a = 0; a < 4; a++)
                    kv[a] = *(const float4*)&ki[(size_t)(k0 + a) * DI + d0];
#pragma unroll
                for (int h = 0; h < HI; h++) {
                    float4 qv = *(const float4*)&qis[h * DI + d0];
#pragma unroll
                    for (int a = 0; a < 4; a++) {
                        acc[a][h] += qv.x * kv[a].x + qv.y * kv[a].y +
                                     qv.z * kv[a].z + qv.w * kv[a].w;
                    }
                }
            }
#pragma unroll
            for (int a = 0; a < 4; a++) {
                int k = k0 + a;
                if (k < ncand) {
                    float s = 0.f;
#pragma unroll
                    for (int h = 0; h < HI; h++) s += wsh[h] * fmaxf(acc[a][h], 0.f);
                    scores[k] = s;
                }
            }
        }
    }
    __syncthreads();

    if (ncand <= K) {
        for (int j = tid; j < KSEL; j += 256) {
            if (j < ncand) {
                topk_idx[q * KSEL + j]   = j;
                topk_score[q * KSEL + j] = scores[j];
            } else {
                topk_idx[q * KSEL + j]   = -1;
                topk_score[q * KSEL + j] = -INFINITY;
            }
        }
        return;
    }

    unsigned int prefix = 0;
    int need = K;
    int cgt  = 0;
    for (int pass = 0; pass < 4; ++pass) {
        const int shift = 24 - pass * 8;
        for (int b = tid; b < 256; b += 256) bins[b] = 0;
        __syncthreads();
        const unsigned int himask = (pass == 0) ? 0u : (0xFFFFFFFFu << (shift + 8));
        for (int k = tid; k < ncand; k += 256) {
            unsigned int u = __float_as_uint(scores[k]);
            if ((u & himask) == prefix) atomicAdd(&bins[(u >> shift) & 0xFF], 1u);
        }
        __syncthreads();
        if (tid == 0) {
            int nd = need, acc_gt = 0, b;
            for (b = 255; b >= 1; --b) {
                int c = (int)bins[b];
                if (c >= nd) break;
                nd -= c; acc_gt += c;
            }
            sh_u[0] = prefix | ((unsigned int)b << shift);
            sh_u[1] = (unsigned int)nd;
            sh_u[2] = (unsigned int)acc_gt;
        }
        __syncthreads();
        prefix = sh_u[0];
        need   = (int)sh_u[1];
        cgt   += (int)sh_u[2];
        __syncthreads();
    }
    const unsigned int ueqT = prefix;
    const int count_eq = (int)bins[ueqT & 0xFF];
    __syncthreads();
    if (tid == 0) cnt = 0;
    __syncthreads();

    for (int k = tid; k < ncand; k += 256) {
        unsigned int u = __float_as_uint(scores[k]);
        if (u > ueqT) {
            unsigned int slot = atomicAdd(&cnt, 1u);
            topk_idx[q * KSEL + slot]   = k;
            topk_score[q * KSEL + slot] = scores[k];
        }
    }
    __syncthreads();
    if (count_eq == need) {
        for (int k = tid; k < ncand; k += 256) {
            if (__float_as_uint(scores[k]) == ueqT) {
                unsigned int slot = atomicAdd(&cnt, 1u);
                topk_idx[q * KSEL + slot]   = k;
                topk_score[q * KSEL + slot] = __uint_as_float(ueqT);
            }
        }
    } else if (tid == 0) {
        int emitted = 0;
        for (int k = 0; k < ncand && emitted < need; ++k) {
            if (__float_as_uint(scores[k]) == ueqT) {
                unsigned int slot = atomicAdd(&cnt, 1u);
                topk_idx[q * KSEL + slot]   = k;
                topk_score[q * KSEL + slot] = __uint_as_float(ueqT);
                emitted++;
            }
        }
    }
}

// ---------------- Kernel B: one block per (q, h), coalesced gather SDPA ----------------
// grid = (S, HQ); h is the slow grid index so in-flight blocks share one head's
// K/V (2 MB) -> L2-resident gathers.
__global__ __launch_bounds__(256) void sparse_attn2(
    const float* __restrict__ Q,    // [HQ, S, D]
    const float* __restrict__ Km,   // [HQ, S, D]
    const float* __restrict__ V,    // [HQ, S, D]
    const int* __restrict__ topk_idx,
    const int* __restrict__ topk_p, const int* __restrict__ endpos_p,
    float* __restrict__ out,        // [HQ, S, D]
    float* __restrict__ aacc_g)     // [S, KSEL] head-summed attn (atomic)
{
    const int q   = blockIdx.x;
    const int h   = blockIdx.y;
    const int tid = threadIdx.x;
    int K = min(topk_p[0], endpos_p[0]);
    K = min(K, KSEL);
    const int n = min(q + 1, K);
    const float scale = 0.08838834764831845f; // 1/sqrt(128)

    __shared__ float qvec[D];
    __shared__ int   idxs[KSEL];
    __shared__ float sc[KSEL];
    __shared__ float opart[8][D];   // 4 KB
    __shared__ float tmp[4];

    if (tid < 32)
        *(float4*)&qvec[tid * 4] = *(const float4*)&Q[((size_t)h * S + q) * D + tid * 4];
    for (int j = tid; j < n; j += 256) idxs[j] = topk_idx[q * KSEL + j];
    __syncthreads();

    // ---- QK: 16 lanes per key row, 512B contiguous per row ----
    const int l16 = tid & 15, grp = tid >> 4;   // 16 row-groups
    const float4 q1 = *(const float4*)&qvec[l16 * 4];
    const float4 q2 = *(const float4*)&qvec[64 + l16 * 4];
    float lmax = -INFINITY;
    for (int j = grp; j < n; j += 16) {
        const float* kr = &Km[((size_t)h * S + idxs[j]) * D];
        float4 k1 = *(const float4*)&kr[l16 * 4];
        float4 k2 = *(const float4*)&kr[64 + l16 * 4];
        float acc = q1.x * k1.x + q1.y * k1.y + q1.z * k1.z + q1.w * k1.w
                  + q2.x * k2.x + q2.y * k2.y + q2.z * k2.z + q2.w * k2.w;
        acc += __shfl_xor(acc, 1);
        acc += __shfl_xor(acc, 2);
        acc += __shfl_xor(acc, 4);
        acc += __shfl_xor(acc, 8);
        float s = acc * scale;
        if (l16 == 0) sc[j] = s;
        lmax = fmaxf(lmax, s);
    }
    const float m = blockReduceMax(lmax, tmp);

    float lsum = 0.f;
    for (int j = tid; j < n; j += 256) {
        float p = expf(sc[j] - m);
        sc[j] = p;
        lsum += p;
    }
    lsum = blockReduceSum(lsum, tmp);
    const float inv = 1.f / lsum;
    for (int j = tid; j < n; j += 256) {
        float p = sc[j] * inv;
        sc[j] = p;
        atomicAdd(&aacc_g[(size_t)q * KSEL + j], p);
    }
    __syncthreads();

    // ---- PV: 32 lanes over d per row, 8 j-groups ----
    const int jg = tid >> 5, lD = (tid & 31) * 4;
    float4 o4 = make_float4(0.f, 0.f, 0.f, 0.f);
    for (int j = jg; j < n; j += 8) {
        const float p = sc[j];
        float4 vv = *(const float4*)&V[((size_t)h * S + idxs[j]) * D + lD];
        o4.x += p * vv.x; o4.y += p * vv.y; o4.z += p * vv.z; o4.w += p * vv.w;
    }
    *(float4*)&opart[jg][lD] = o4;
    __syncthreads();
    if (tid < D) {
        float o = 0.f;
#pragma unroll
        for (int p8 = 0; p8 < 8; ++p8) o += opart[p8][tid];
        out[((size_t)h * S + q) * D + tid] = o;
    }
}

// ---------------- Kernel B2: per-row KL loss ----------------
__global__ __launch_bounds__(256) void row_loss(
    const float* __restrict__ aacc_g,     // [S, KSEL]
    const float* __restrict__ topk_score, // [S, KSEL]
    const int* __restrict__ topk_p, const int* __restrict__ endpos_p,
    float* __restrict__ rowloss)          // [S]
{
    const int q   = blockIdx.x;
    const int tid = threadIdx.x;
    int K = min(topk_p[0], endpos_p[0]);
    K = min(K, KSEL);
    const int n = min(q + 1, K);

    __shared__ float sc[KSEL];
    __shared__ float aacc[KSEL];
    __shared__ float tmp[4];

    for (int j = tid; j < n; j += 256) aacc[j] = aacc_g[(size_t)q * KSEL + j];

    float tmaxl = -INFINITY;
    for (int j = tid; j < n; j += 256) {
        float t = topk_score[q * KSEL + j];
        sc[j] = t;
        tmaxl = fmaxf(tmaxl, t);
    }
    const float tm = blockReduceMax(tmaxl, tmp);
    float tsum = 0.f;
    for (int j = tid; j < n; j += 256) {
        float e = expf(sc[j] - tm);
        sc[j] = e;
        tsum += e;
    }
    tsum = blockReduceSum(tsum, tmp);
    const float tinv = 1.f / tsum;

    float sa = 0.f;
    for (int j = tid; j < n; j += 256) sa += fabsf(aacc[j]);
    sa = blockReduceSum(sa, tmp);
    const float denom = fmaxf(sa, 1e-12f);

    float kl = 0.f;
    for (int j = tid; j < n; j += 256) {
        float tgt = aacc[j] / denom + 1e-8f;
        float pd  = sc[j] * tinv + 1e-8f;
        kl += tgt * (logf(tgt) - logf(pd));
    }
    kl = blockReduceSum(kl, tmp);
    if (tid == 0) rowloss[q] = kl;
}

// ---------------- Kernel C: loss = mean over rows ----------------
__global__ __launch_bounds__(256) void reduce_loss(const float* __restrict__ rowloss,
                                                   float* __restrict__ out) {
    __shared__ float tmp[4];
    float v = 0.f;
    for (int i = threadIdx.x; i < S; i += 256) v += rowloss[i];
    v = blockReduceSum(v, tmp);
    if (threadIdx.x == 0) out[0] = v / (float)S;
}

extern "C" void kernel_launch(void* const* d_in, const int* in_sizes, int n_in,
                              void* d_out, int out_size, void* d_ws, size_t ws_size,
                              hipStream_t stream) {
    const float* q   = (const float*)d_in[0];
    const float* k   = (const float*)d_in[1];
    const float* v   = (const float*)d_in[2];
    const float* qi  = (const float*)d_in[3];
    const float* ki  = (const float*)d_in[4];
    const float* w   = (const float*)d_in[5];
    const int* topk  = (const int*)d_in[6];
    const int* endp  = (const int*)d_in[7];
    float* out = (float*)d_out;

    char* ws = (char*)d_ws;
    int*   topk_idx   = (int*)ws;                                   // 4 MB
    float* topk_score = (float*)(ws + (size_t)S * KSEL * 4);        // 4 MB
    float* aacc_g     = (float*)(ws + (size_t)S * KSEL * 8);        // 4 MB
    float* rowloss    = (float*)(ws + (size_t)S * KSEL * 12);       // 8 KB

    hipLaunchKernelGGL(indexer_topk, dim3(S), dim3(256), 0, stream,
                       qi, ki, w, topk, endp, topk_idx, topk_score);
    hipMemsetAsync(aacc_g, 0, (size_t)S * KSEL * sizeof(float), stream);
    hipLaunchKernelGGL(sparse_attn2, dim3(S, HQ), dim3(256), 0, stream,
                       q, k, v, topk_idx, topk, endp, out + 1, aacc_g);
    hipLaunchKernelGGL(row_loss, dim3(S), dim3(256), 0, stream,
                       aacc_g, topk_score, topk, endp, rowloss);
    hipLaunchKernelGGL(reduce_loss, dim3(1), dim3(256), 0, stream,
                       rowloss, out);
}

// Round 5
// 762.393 us; speedup vs baseline: 3.6588x; 1.1384x over previous
//
#include <hip/hip_runtime.h>
#include <hip/hip_bf16.h>
#include <math.h>

#define S    2048
#define HQ   16
#define D    128
#define HI   16
#define DI   128
#define KSEL 512

// ---------------- reductions (wave = 64) ----------------
__device__ __forceinline__ float waveReduceSum(float v) {
#pragma unroll
    for (int o = 32; o > 0; o >>= 1) v += __shfl_down(v, o);
    return v;
}
__device__ __forceinline__ float waveReduceMax(float v) {
#pragma unroll
    for (int o = 32; o > 0; o >>= 1) v = fmaxf(v, __shfl_down(v, o));
    return v;
}
__device__ __forceinline__ float blockReduceSum(float v, float* tmp) {
    int wid = threadIdx.x >> 6, lane = threadIdx.x & 63;
    v = waveReduceSum(v);
    __syncthreads();
    if (lane == 0) tmp[wid] = v;
    __syncthreads();
    return tmp[0] + tmp[1] + tmp[2] + tmp[3];
}
__device__ __forceinline__ float blockReduceMax(float v, float* tmp) {
    int wid = threadIdx.x >> 6, lane = threadIdx.x & 63;
    v = waveReduceMax(v);
    __syncthreads();
    if (lane == 0) tmp[wid] = v;
    __syncthreads();
    return fmaxf(fmaxf(tmp[0], tmp[1]), fmaxf(tmp[2], tmp[3]));
}

__device__ __forceinline__ unsigned short f2bf(float f) {  // RNE
    unsigned int u = __float_as_uint(f);
    return (unsigned short)((u + 0x7FFFu + ((u >> 16) & 1u)) >> 16);
}
// unpack 8 bf16 (16B, loaded as float4) -> 8 f32
__device__ __forceinline__ void bf8_unpack(float4 raw, float* v) {
    unsigned int u0 = __float_as_uint(raw.x), u1 = __float_as_uint(raw.y);
    unsigned int u2 = __float_as_uint(raw.z), u3 = __float_as_uint(raw.w);
    v[0] = __uint_as_float(u0 << 16); v[1] = __uint_as_float(u0 & 0xFFFF0000u);
    v[2] = __uint_as_float(u1 << 16); v[3] = __uint_as_float(u1 & 0xFFFF0000u);
    v[4] = __uint_as_float(u2 << 16); v[5] = __uint_as_float(u2 & 0xFFFF0000u);
    v[6] = __uint_as_float(u3 << 16); v[7] = __uint_as_float(u3 & 0xFFFF0000u);
}

// ---------------- f32 -> bf16 bulk convert (grid-stride, float4 in / ushort4 out) ----------------
__global__ __launch_bounds__(256) void f32_to_bf16(const float* __restrict__ in,
                                                   unsigned short* __restrict__ outp,
                                                   int n4) {
    for (int i = blockIdx.x * 256 + threadIdx.x; i < n4; i += gridDim.x * 256) {
        float4 x = ((const float4*)in)[i];
        ushort4 r;
        r.x = f2bf(x.x); r.y = f2bf(x.y); r.z = f2bf(x.z); r.w = f2bf(x.w);
        ((ushort4*)outp)[i] = r;
    }
}

// ---------------- Kernel A: indexer row + radix top-k (unchanged) ----------------
__global__ __launch_bounds__(256) void indexer_topk(
    const float* __restrict__ qi,   // [S, HI, DI]
    const float* __restrict__ ki,   // [S, DI]
    const float* __restrict__ w,    // [S, HI]
    const int* __restrict__ topk_p, const int* __restrict__ endpos_p,
    int* __restrict__ topk_idx,     // [S, KSEL]
    float* __restrict__ topk_score) // [S, KSEL]
{
    const int q   = blockIdx.x;
    const int tid = threadIdx.x;
    int K = min(topk_p[0], endpos_p[0]);
    K = min(K, KSEL);

    __shared__ float qis[HI * DI];
    __shared__ float wsh[HI];
    __shared__ float scores[S];
    __shared__ unsigned int bins[256];
    __shared__ unsigned int sh_u[3];
    __shared__ unsigned int cnt;

    for (int i = tid; i < HI * DI; i += 256) qis[i] = qi[(size_t)q * HI * DI + i];
    if (tid < HI) wsh[tid] = w[q * HI + tid];
    __syncthreads();

    const int ncand = q + 1;

    for (int kbase = 0; kbase < ncand; kbase += 1024) {
        const int k0 = kbase + tid * 4;
        if (k0 < ncand) {
            float acc[4][HI];
#pragma unroll
            for (int a = 0; a < 4; a++)
#pragma unroll
                for (int h = 0; h < HI; h++) acc[a][h] = 0.f;
            for (int d0 = 0; d0 < DI; d0 += 4) {
                float4 kv[4];
#pragma unroll
                for (int a = 0; a < 4; a++)
                    kv[a] = *(const float4*)&ki[(size_t)(k0 + a) * DI + d0];
#pragma unroll
                for (int h = 0; h < HI; h++) {
                    float4 qv = *(const float4*)&qis[h * DI + d0];
#pragma unroll
                    for (int a = 0; a < 4; a++) {
                        acc[a][h] += qv.x * kv[a].x + qv.y * kv[a].y +
                                     qv.z * kv[a].z + qv.w * kv[a].w;
                    }
                }
            }
#pragma unroll
            for (int a = 0; a < 4; a++) {
                int k = k0 + a;
                if (k < ncand) {
                    float s = 0.f;
#pragma unroll
                    for (int h = 0; h < HI; h++) s += wsh[h] * fmaxf(acc[a][h], 0.f);
                    scores[k] = s;
                }
            }
        }
    }
    __syncthreads();

    if (ncand <= K) {
        for (int j = tid; j < KSEL; j += 256) {
            if (j < ncand) {
                topk_idx[q * KSEL + j]   = j;
                topk_score[q * KSEL + j] = scores[j];
            } else {
                topk_idx[q * KSEL + j]   = -1;
                topk_score[q * KSEL + j] = -INFINITY;
            }
        }
        return;
    }

    unsigned int prefix = 0;
    int need = K;
    int cgt  = 0;
    for (int pass = 0; pass < 4; ++pass) {
        const int shift = 24 - pass * 8;
        for (int b = tid; b < 256; b += 256) bins[b] = 0;
        __syncthreads();
        const unsigned int himask = (pass == 0) ? 0u : (0xFFFFFFFFu << (shift + 8));
        for (int k = tid; k < ncand; k += 256) {
            unsigned int u = __float_as_uint(scores[k]);
            if ((u & himask) == prefix) atomicAdd(&bins[(u >> shift) & 0xFF], 1u);
        }
        __syncthreads();
        if (tid == 0) {
            int nd = need, acc_gt = 0, b;
            for (b = 255; b >= 1; --b) {
                int c = (int)bins[b];
                if (c >= nd) break;
                nd -= c; acc_gt += c;
            }
            sh_u[0] = prefix | ((unsigned int)b << shift);
            sh_u[1] = (unsigned int)nd;
            sh_u[2] = (unsigned int)acc_gt;
        }
        __syncthreads();
        prefix = sh_u[0];
        need   = (int)sh_u[1];
        cgt   += (int)sh_u[2];
        __syncthreads();
    }
    const unsigned int ueqT = prefix;
    const int count_eq = (int)bins[ueqT & 0xFF];
    __syncthreads();
    if (tid == 0) cnt = 0;
    __syncthreads();

    for (int k = tid; k < ncand; k += 256) {
        unsigned int u = __float_as_uint(scores[k]);
        if (u > ueqT) {
            unsigned int slot = atomicAdd(&cnt, 1u);
            topk_idx[q * KSEL + slot]   = k;
            topk_score[q * KSEL + slot] = scores[k];
        }
    }
    __syncthreads();
    if (count_eq == need) {
        for (int k = tid; k < ncand; k += 256) {
            if (__float_as_uint(scores[k]) == ueqT) {
                unsigned int slot = atomicAdd(&cnt, 1u);
                topk_idx[q * KSEL + slot]   = k;
                topk_score[q * KSEL + slot] = __uint_as_float(ueqT);
            }
        }
    } else if (tid == 0) {
        int emitted = 0;
        for (int k = 0; k < ncand && emitted < need; ++k) {
            if (__float_as_uint(scores[k]) == ueqT) {
                unsigned int slot = atomicAdd(&cnt, 1u);
                topk_idx[q * KSEL + slot]   = k;
                topk_score[q * KSEL + slot] = __uint_as_float(ueqT);
                emitted++;
            }
        }
    }
}

// ---------------- Kernel B (bf16): one block per (q, h), 256B/row gathers ----------------
__global__ __launch_bounds__(256) void sparse_attn_bf16(
    const float* __restrict__ Q,            // [HQ, S, D] f32
    const unsigned short* __restrict__ Kb,  // [HQ, S, D] bf16
    const unsigned short* __restrict__ Vb,  // [HQ, S, D] bf16
    const int* __restrict__ topk_idx,
    const int* __restrict__ topk_p, const int* __restrict__ endpos_p,
    float* __restrict__ out,                // [HQ, S, D] f32
    float* __restrict__ aacc_g)             // [S, KSEL]
{
    const int q   = blockIdx.x;
    const int h   = blockIdx.y;
    const int tid = threadIdx.x;
    int K = min(topk_p[0], endpos_p[0]);
    K = min(K, KSEL);
    const int n = min(q + 1, K);
    const float scale = 0.08838834764831845f;

    __shared__ float qvec[D];
    __shared__ int   idxs[KSEL];
    __shared__ float sc[KSEL];
    __shared__ float opart[16][D];   // 8 KB
    __shared__ float tmp[4];

    if (tid < 32)
        *(float4*)&qvec[tid * 4] = *(const float4*)&Q[((size_t)h * S + q) * D + tid * 4];
    for (int j = tid; j < n; j += 256) idxs[j] = topk_idx[q * KSEL + j];
    __syncthreads();

    // ---- QK: 16 lanes per key row; each lane loads 8 bf16 (16B) -> full 256B row/group ----
    const int l16 = tid & 15, grp = tid >> 4;   // 16 row-groups
    const float4 qa = *(const float4*)&qvec[l16 * 8];
    const float4 qb = *(const float4*)&qvec[l16 * 8 + 4];
    float lmax = -INFINITY;
    for (int j = grp; j < n; j += 16) {
        float4 raw = *(const float4*)&Kb[((size_t)h * S + idxs[j]) * D + l16 * 8];
        float kv[8];
        bf8_unpack(raw, kv);
        float acc = qa.x * kv[0] + qa.y * kv[1] + qa.z * kv[2] + qa.w * kv[3]
                  + qb.x * kv[4] + qb.y * kv[5] + qb.z * kv[6] + qb.w * kv[7];
        acc += __shfl_xor(acc, 1);
        acc += __shfl_xor(acc, 2);
        acc += __shfl_xor(acc, 4);
        acc += __shfl_xor(acc, 8);
        float s = acc * scale;
        if (l16 == 0) sc[j] = s;
        lmax = fmaxf(lmax, s);
    }
    const float m = blockReduceMax(lmax, tmp);

    float lsum = 0.f;
    for (int j = tid; j < n; j += 256) {
        float p = expf(sc[j] - m);
        sc[j] = p;
        lsum += p;
    }
    lsum = blockReduceSum(lsum, tmp);
    const float inv = 1.f / lsum;
    for (int j = tid; j < n; j += 256) {
        float p = sc[j] * inv;
        sc[j] = p;
        atomicAdd(&aacc_g[(size_t)q * KSEL + j], p);
    }
    __syncthreads();

    // ---- PV: same 16-group mapping; lane owns d = l16*8 .. +8 ----
    float o[8];
#pragma unroll
    for (int i = 0; i < 8; i++) o[i] = 0.f;
    for (int j = grp; j < n; j += 16) {
        const float p = sc[j];
        float4 raw = *(const float4*)&Vb[((size_t)h * S + idxs[j]) * D + l16 * 8];
        float vv[8];
        bf8_unpack(raw, vv);
#pragma unroll
        for (int i = 0; i < 8; i++) o[i] += p * vv[i];
    }
#pragma unroll
    for (int i = 0; i < 8; i++) opart[grp][l16 * 8 + i] = o[i];
    __syncthreads();
    if (tid < D) {
        float s = 0.f;
#pragma unroll
        for (int p16 = 0; p16 < 16; ++p16) s += opart[p16][tid];
        out[((size_t)h * S + q) * D + tid] = s;
    }
}

// ---------------- Kernel B (f32 fallback, ws too small) ----------------
__global__ __launch_bounds__(256) void sparse_attn2(
    const float* __restrict__ Q,
    const float* __restrict__ Km,
    const float* __restrict__ V,
    const int* __restrict__ topk_idx,
    const int* __restrict__ topk_p, const int* __restrict__ endpos_p,
    float* __restrict__ out,
    float* __restrict__ aacc_g)
{
    const int q   = blockIdx.x;
    const int h   = blockIdx.y;
    const int tid = threadIdx.x;
    int K = min(topk_p[0], endpos_p[0]);
    K = min(K, KSEL);
    const int n = min(q + 1, K);
    const float scale = 0.08838834764831845f;

    __shared__ float qvec[D];
    __shared__ int   idxs[KSEL];
    __shared__ float sc[KSEL];
    __shared__ float opart[8][D];
    __shared__ float tmp[4];

    if (tid < 32)
        *(float4*)&qvec[tid * 4] = *(const float4*)&Q[((size_t)h * S + q) * D + tid * 4];
    for (int j = tid; j < n; j += 256) idxs[j] = topk_idx[q * KSEL + j];
    __syncthreads();

    const int l16 = tid & 15, grp = tid >> 4;
    const float4 q1 = *(const float4*)&qvec[l16 * 4];
    const float4 q2 = *(const float4*)&qvec[64 + l16 * 4];
    float lmax = -INFINITY;
    for (int j = grp; j < n; j += 16) {
        const float* kr = &Km[((size_t)h * S + idxs[j]) * D];
        float4 k1 = *(const float4*)&kr[l16 * 4];
        float4 k2 = *(const float4*)&kr[64 + l16 * 4];
        float acc = q1.x * k1.x + q1.y * k1.y + q1.z * k1.z + q1.w * k1.w
                  + q2.x * k2.x + q2.y * k2.y + q2.z * k2.z + q2.w * k2.w;
        acc += __shfl_xor(acc, 1);
        acc += __shfl_xor(acc, 2);
        acc += __shfl_xor(acc, 4);
        acc += __shfl_xor(acc, 8);
        float s = acc * scale;
        if (l16 == 0) sc[j] = s;
        lmax = fmaxf(lmax, s);
    }
    const float m = blockReduceMax(lmax, tmp);

    float lsum = 0.f;
    for (int j = tid; j < n; j += 256) {
        float p = expf(sc[j] - m);
        sc[j] = p;
        lsum += p;
    }
    lsum = blockReduceSum(lsum, tmp);
    const float inv = 1.f / lsum;
    for (int j = tid; j < n; j += 256) {
        float p = sc[j] * inv;
        sc[j] = p;
        atomicAdd(&aacc_g[(size_t)q * KSEL + j], p);
    }
    __syncthreads();

    const int jg = tid >> 5, lD = (tid & 31) * 4;
    float4 o4 = make_float4(0.f, 0.f, 0.f, 0.f);
    for (int j = jg; j < n; j += 8) {
        const float p = sc[j];
        float4 vv = *(const float4*)&V[((size_t)h * S + idxs[j]) * D + lD];
        o4.x += p * vv.x; o4.y += p * vv.y; o4.z += p * vv.z; o4.w += p * vv.w;
    }
    *(float4*)&opart[jg][lD] = o4;
    __syncthreads();
    if (tid < D) {
        float o = 0.f;
#pragma unroll
        for (int p8 = 0; p8 < 8; ++p8) o += opart[p8][tid];
        out[((size_t)h * S + q) * D + tid] = o;
    }
}

// ---------------- Kernel B2: per-row KL loss ----------------
__global__ __launch_bounds__(256) void row_loss(
    const float* __restrict__ aacc_g,
    const float* __restrict__ topk_score,
    const int* __restrict__ topk_p, const int* __restrict__ endpos_p,
    float* __restrict__ rowloss)
{
    const int q   = blockIdx.x;
    const int tid = threadIdx.x;
    int K = min(topk_p[0], endpos_p[0]);
    K = min(K, KSEL);
    const int n = min(q + 1, K);

    __shared__ float sc[KSEL];
    __shared__ float aacc[KSEL];
    __shared__ float tmp[4];

    for (int j = tid; j < n; j += 256) aacc[j] = aacc_g[(size_t)q * KSEL + j];

    float tmaxl = -INFINITY;
    for (int j = tid; j < n; j += 256) {
        float t = topk_score[q * KSEL + j];
        sc[j] = t;
        tmaxl = fmaxf(tmaxl, t);
    }
    const float tm = blockReduceMax(tmaxl, tmp);
    float tsum = 0.f;
    for (int j = tid; j < n; j += 256) {
        float e = expf(sc[j] - tm);
        sc[j] = e;
        tsum += e;
    }
    tsum = blockReduceSum(tsum, tmp);
    const float tinv = 1.f / tsum;

    float sa = 0.f;
    for (int j = tid; j < n; j += 256) sa += fabsf(aacc[j]);
    sa = blockReduceSum(sa, tmp);
    const float denom = fmaxf(sa, 1e-12f);

    float kl = 0.f;
    for (int j = tid; j < n; j += 256) {
        float tgt = aacc[j] / denom + 1e-8f;
        float pd  = sc[j] * tinv + 1e-8f;
        kl += tgt * (logf(tgt) - logf(pd));
    }
    kl = blockReduceSum(kl, tmp);
    if (tid == 0) rowloss[q] = kl;
}

// ---------------- Kernel C: loss = mean over rows ----------------
__global__ __launch_bounds__(256) void reduce_loss(const float* __restrict__ rowloss,
                                                   float* __restrict__ out) {
    __shared__ float tmp[4];
    float v = 0.f;
    for (int i = threadIdx.x; i < S; i += 256) v += rowloss[i];
    v = blockReduceSum(v, tmp);
    if (threadIdx.x == 0) out[0] = v / (float)S;
}

extern "C" void kernel_launch(void* const* d_in, const int* in_sizes, int n_in,
                              void* d_out, int out_size, void* d_ws, size_t ws_size,
                              hipStream_t stream) {
    const float* q   = (const float*)d_in[0];
    const float* k   = (const float*)d_in[1];
    const float* v   = (const float*)d_in[2];
    const float* qi  = (const float*)d_in[3];
    const float* ki  = (const float*)d_in[4];
    const float* w   = (const float*)d_in[5];
    const int* topk  = (const int*)d_in[6];
    const int* endp  = (const int*)d_in[7];
    float* out = (float*)d_out;

    char* ws = (char*)d_ws;
    const size_t SZ_IDX = (size_t)S * KSEL * 4;   // 4 MB each
    int*   topk_idx   = (int*)ws;
    float* topk_score = (float*)(ws + SZ_IDX);
    float* aacc_g     = (float*)(ws + 2 * SZ_IDX);
    float* rowloss    = (float*)(ws + 3 * SZ_IDX);
    char*  bf_base    = ws + 3 * SZ_IDX + 65536;
    unsigned short* Kb = (unsigned short*)bf_base;                        // 8 MB
    unsigned short* Vb = (unsigned short*)(bf_base + (size_t)HQ * S * D * 2); // 8 MB
    const size_t need = 3 * SZ_IDX + 65536 + 2 * (size_t)HQ * S * D * 2;

    hipLaunchKernelGGL(indexer_topk, dim3(S), dim3(256), 0, stream,
                       qi, ki, w, topk, endp, topk_idx, topk_score);
    hipMemsetAsync(aacc_g, 0, (size_t)S * KSEL * sizeof(float), stream);

    if (ws_size >= need) {
        const int n4 = HQ * S * D / 4;
        hipLaunchKernelGGL(f32_to_bf16, dim3(2048), dim3(256), 0, stream, k, Kb, n4);
        hipLaunchKernelGGL(f32_to_bf16, dim3(2048), dim3(256), 0, stream, v, Vb, n4);
        hipLaunchKernelGGL(sparse_attn_bf16, dim3(S, HQ), dim3(256), 0, stream,
                           q, Kb, Vb, topk_idx, topk, endp, out + 1, aacc_g);
    } else {
        hipLaunchKernelGGL(sparse_attn2, dim3(S, HQ), dim3(256), 0, stream,
                           q, k, v, topk_idx, topk, endp, out + 1, aacc_g);
    }
    hipLaunchKernelGGL(row_loss, dim3(S), dim3(256), 0, stream,
                       aacc_g, topk_score, topk, endp, rowloss);
    hipLaunchKernelGGL(reduce_loss, dim3(1), dim3(256), 0, stream,
                       rowloss, out);
}